// Round 12
// baseline (380.786 us; speedup 1.0000x reference)
//
#include <hip/hip_runtime.h>
#include <hip/hip_bf16.h>

// Problem: B=8192, D_IN=1024, D_OUT=1024, E=16
#define NB 8192
#define DIN 1024
#define DOUT 1024
#define NE 16

// GEMM tile geometry: split-K=2 (8 experts/block), BM=BN=256, BK=32, quad-buf
#define BM 256
#define BN 256
#define BK 32
#define NT 256  // (8 experts * 1024) / 32

typedef __attribute__((ext_vector_type(8))) short bf16x8;
typedef __attribute__((ext_vector_type(4))) short short4_t;
typedef __attribute__((ext_vector_type(4))) float f32x4;

__device__ __forceinline__ unsigned short f32_to_bf16(float f) {
  unsigned int u = __float_as_uint(f);
  u += 0x7FFFu + ((u >> 16) & 1u);  // RNE
  return (unsigned short)(u >> 16);
}

__device__ __forceinline__ void gl_lds16(const void* gp, void* lp) {
  __builtin_amdgcn_global_load_lds(
      (const __attribute__((address_space(1))) void*)gp,
      (__attribute__((address_space(3))) void*)lp, 16, 0, 0);
}

#define SB __builtin_amdgcn_sched_barrier(0)

// ---------------- Kernel 1: gate softmax (f32) + x -> bf16 cast --------------
__global__ __launch_bounds__(256) void gate_cast_kernel(
    const float* __restrict__ x, const float* __restrict__ Wg,
    const float* __restrict__ bg, float* __restrict__ gout,
    unsigned short* __restrict__ xbf) {
  const int lane = threadIdx.x & 63;
  const int wid = threadIdx.x >> 6;
  const int row = blockIdx.x * 4 + wid;

  const f32x4* xr = (const f32x4*)(x + (size_t)row * DIN);
  f32x4 xv[4];
#pragma unroll
  for (int j = 0; j < 4; ++j) xv[j] = xr[j * 64 + lane];

  float acc[NE];
#pragma unroll
  for (int e = 0; e < NE; ++e) acc[e] = 0.f;

#pragma unroll
  for (int j = 0; j < 4; ++j) {
#pragma unroll
    for (int t = 0; t < 4; ++t) {
      const int i = j * 256 + lane * 4 + t;
      const f32x4* wrow = (const f32x4*)(Wg + (size_t)i * NE);
      const f32x4 w0 = wrow[0], w1 = wrow[1], w2 = wrow[2], w3 = wrow[3];
      const float xx = xv[j][t];
#pragma unroll
      for (int q = 0; q < 4; ++q) {
        acc[q]      = fmaf(xx, w0[q], acc[q]);
        acc[4 + q]  = fmaf(xx, w1[q], acc[4 + q]);
        acc[8 + q]  = fmaf(xx, w2[q], acc[8 + q]);
        acc[12 + q] = fmaf(xx, w3[q], acc[12 + q]);
      }
    }
  }
#pragma unroll
  for (int off = 32; off >= 1; off >>= 1) {
#pragma unroll
    for (int e = 0; e < NE; ++e) acc[e] += __shfl_xor(acc[e], off, 64);
  }
#pragma unroll
  for (int e = 0; e < NE; ++e) acc[e] += bg[e];
  float mx = acc[0];
#pragma unroll
  for (int e = 1; e < NE; ++e) mx = fmaxf(mx, acc[e]);
  float p[NE];
  float s = 0.f;
#pragma unroll
  for (int e = 0; e < NE; ++e) { p[e] = expf(acc[e] - mx); s += p[e]; }
  const float inv = 1.f / s;
  if (lane == 0) {
#pragma unroll
    for (int e = 0; e < NE; ++e) gout[(size_t)row * NE + e] = p[e] * inv;
  }
#pragma unroll
  for (int j = 0; j < 4; ++j) {
    short4_t o;
#pragma unroll
    for (int t = 0; t < 4; ++t) o[t] = (short)f32_to_bf16(xv[j][t]);
    *(short4_t*)(xbf + (size_t)row * DIN + j * 256 + lane * 4) = o;
  }
}

// ------------- Kernel 2: We[e,i,o] f32 -> WeT[e,o,i] bf16 (transpose) --------
__global__ __launch_bounds__(256) void we_transpose_kernel(
    const float* __restrict__ We, unsigned short* __restrict__ WeT) {
  __shared__ float tile[64][65];
  const int e = blockIdx.z, it = blockIdx.y, ot = blockIdx.x;
  const int tr = threadIdx.x >> 4;
  const int tc = (threadIdx.x & 15) * 4;
  const float* src = We + (((size_t)e * DIN + it * 64) * DOUT) + ot * 64;
#pragma unroll
  for (int rr = 0; rr < 64; rr += 16) {
    const f32x4 v = *(const f32x4*)(src + (size_t)(rr + tr) * DOUT + tc);
#pragma unroll
    for (int t = 0; t < 4; ++t) tile[rr + tr][tc + t] = v[t];
  }
  __syncthreads();
  unsigned short* dst = WeT + (((size_t)e * DOUT + ot * 64) * DIN) + it * 64;
#pragma unroll
  for (int rr = 0; rr < 64; rr += 16) {
    short4_t o;
#pragma unroll
    for (int t = 0; t < 4; ++t) o[t] = (short)f32_to_bf16(tile[tc + t][rr + tr]);
    *(short4_t*)(dst + (size_t)(rr + tr) * DIN + tc) = o;
  }
}

// ---- Kernel 3: split-K MoE GEMM, BK=32, quad-buffer, depth-3 prefetch ------
// 8 waves 2Mx4N, per-wave 128x64 = 8mi x 4ni of 16x16x32 (single ks).
// Per tile: P0 {read B4+A4 | stage 2 of t+3 | bar | 16 MFMA}
//           P1 {read A4    | stage 2 of t+3 | bar | 16 MFMA}
//           boundary {vmcnt(8) | bar}   -- drains t+1 (issued 2 tiles ago,
//                                          ~4000cyc: HBM latency covered)
// Output: atomicAdd into pre-zeroed out; bias folded per half in epilogue.
__global__ __launch_bounds__(512, 2) void moe_gemm_kernel(
    const unsigned short* __restrict__ xbf,   // [8192][1024] bf16
    const unsigned short* __restrict__ WeT,   // [16][1024 o][1024 i] bf16
    const float* __restrict__ g,              // [8192][16]
    const float* __restrict__ be,             // [16][1024]
    float* __restrict__ out) {                // [8192][1024] f32 (zeroed)
  __shared__ __align__(16) unsigned short As[4][BM * BK];  // 4x16 KiB
  __shared__ __align__(16) unsigned short Bs[4][BN * BK];  // 4x16 KiB
  __shared__ float gs[BM][NE];                             // 16 KiB

  const int tid = threadIdx.x;
  const int lane = tid & 63, wid = tid >> 6;
  const int wm = wid >> 2, wn = wid & 3;
  const int l15 = lane & 15, l4 = lane >> 4;

  const int bid = blockIdx.x;
  const int xcd = bid & 7, jj_ = bid >> 3;
  const int kh = xcd >> 2;
  const int brow = ((xcd & 3) * 8 + (jj_ >> 2)) * BM;
  const int bcol = (jj_ & 3) * BN;

  // LDS read bases: row = 64B (4 slots of 16B); swizzle slot ^= row&3
  const int rswz = ((l4 ^ (l15 & 3)) << 4);
  const char* const ldsA = (const char*)&As[0][0] + (wm * 128 + l15) * 64 + rswz;
  const char* const ldsB = (const char*)&Bs[0][0] + (wn * 64 + l15) * 64 + rswz;

  // staging (linear LDS dst = wave base + lane*16; inverse-swizzled global src)
  const int srow = tid >> 2;                                    // 0..127
  const int lk = ((((tid & 3) << 4) ^ ((srow & 3) << 4)) >> 1); // k-elem
  const unsigned short* const aBase = xbf + (size_t)(brow + srow) * DIN + lk;
  const unsigned short* const bBase = WeT + (size_t)(bcol + srow) * DIN + lk;
  char* const ldsStA = (char*)&As[0][0] + wid * 1024;  // wave-uniform
  char* const ldsStB = (char*)&Bs[0][0] + wid * 1024;

#define STA(BUF, CR, KC) \
  gl_lds16(aBase + (size_t)(CR) * DIN + (KC), ldsStA + (BUF) * 16384 + (CR) * 64)
#define STB(BUF, CR, EOFF, KC) \
  gl_lds16(bBase + (EOFF) + (size_t)(CR) * DIN + (KC), \
           ldsStB + (BUF) * 16384 + (CR) * 64)
#define RD_B(BUF)                                                  \
  _Pragma("unroll") for (int ni = 0; ni < 4; ++ni)                 \
      bfr[ni] = *(const bf16x8*)(ldsB + ni * 1024 + (BUF) * 16384);
#define RD_A(MI0, BUF)                                             \
  _Pragma("unroll") for (int d = 0; d < 4; ++d)                    \
      af[d] = *(const bf16x8*)(ldsA + ((MI0) + d) * 1024 + (BUF) * 16384);
#define MFMA_P(MI0)                                                \
  _Pragma("unroll") for (int d = 0; d < 4; ++d)                    \
  _Pragma("unroll") for (int ni = 0; ni < 4; ++ni)                 \
      acc[(MI0) + d][ni] = __builtin_amdgcn_mfma_f32_16x16x32_bf16(\
          af[d], bfr[ni], acc[(MI0) + d][ni], 0, 0, 0);

  {  // gate tile -> LDS
    const f32x4* gsrc = (const f32x4*)(g + (size_t)brow * NE);
    f32x4* gdst = (f32x4*)&gs[0][0];
    gdst[tid] = gsrc[tid];
    gdst[tid + 512] = gsrc[tid + 512];
  }

  // prologue: stage tiles 0,1,2 into bufs 0,1,2 (kc = 0,32,64; expert kh*8)
  {
    const size_t e0 = (size_t)(kh * 8) * (size_t)(DIN * DOUT);
    STB(0, 0, e0, 0);  STB(0, 128, e0, 0);  STA(0, 0, 0);  STA(0, 128, 0);
    STB(1, 0, e0, 32); STB(1, 128, e0, 32); STA(1, 0, 32); STA(1, 128, 32);
    STB(2, 0, e0, 64); STB(2, 128, e0, 64); STA(2, 0, 64); STA(2, 128, 64);
  }

  f32x4 acc[8][4];
#pragma unroll
  for (int mi = 0; mi < 8; ++mi)
#pragma unroll
    for (int ni = 0; ni < 4; ++ni) acc[mi][ni] = (f32x4){0.f, 0.f, 0.f, 0.f};

  asm volatile("s_waitcnt vmcnt(8) lgkmcnt(0)" ::: "memory");
  __builtin_amdgcn_s_barrier(); SB;

  bf16x8 bfr[4], af[4];

#define TILE_BODY(T, BUF)                                                      \
  {                                                                            \
    const int t_ = (T);                                                        \
    const int sT = t_ + 3;                                                     \
    const bool doStage = sT < NT;                                              \
    const int bufS = ((BUF) + 3) & 3;                                          \
    const int kcS = (sT & 31) * 32;                                            \
    const size_t eoffS =                                                       \
        (size_t)(kh * 8 + (sT >> 5)) * (size_t)(DIN * DOUT);                   \
    if ((t_ & 31) == 0 && t_ > 0) { /* expert boundary rescale */              \
      const int e = kh * 8 + (t_ >> 5);                                        \
      _Pragma("unroll") for (int mi = 0; mi < 8; ++mi) {                       \
        const int rb = wm * 128 + mi * 16 + l4 * 4;                            \
        _Pragma("unroll") for (int q = 0; q < 4; ++q) {                        \
          const float r = gs[rb + q][e - 1] *                                  \
                          __builtin_amdgcn_rcpf(fmaxf(gs[rb + q][e], 1e-30f)); \
          _Pragma("unroll") for (int ni = 0; ni < 4; ++ni)                     \
              acc[mi][ni][q] *= r;                                             \
        }                                                                      \
      }                                                                        \
    }                                                                          \
    /* ===== P0: mi0-3 ===== */                                                \
    RD_B(BUF); RD_A(0, BUF);                                                   \
    if (doStage) { STB(bufS, 0, eoffS, kcS); STB(bufS, 128, eoffS, kcS); }     \
    __builtin_amdgcn_s_barrier(); SB;                                          \
    __builtin_amdgcn_s_setprio(1); MFMA_P(0);                                  \
    __builtin_amdgcn_s_setprio(0);                                             \
    /* ===== P1: mi4-7 ===== */                                                \
    RD_A(4, BUF);                                                              \
    if (doStage) { STA(bufS, 0, kcS); STA(bufS, 128, kcS); }                   \
    __builtin_amdgcn_s_barrier(); SB;                                          \
    __builtin_amdgcn_s_setprio(1); MFMA_P(4);                                  \
    __builtin_amdgcn_s_setprio(0);                                             \
    if ((t_ & 31) == 31) { /* bias for expert e */                             \
      const int e = kh * 8 + (t_ >> 5);                                        \
      _Pragma("unroll") for (int ni = 0; ni < 4; ++ni) {                       \
        const float bv = be[e * DOUT + bcol + wn * 64 + ni * 16 + l15];        \
        _Pragma("unroll") for (int mi = 0; mi < 8; ++mi)                       \
          _Pragma("unroll") for (int q = 0; q < 4; ++q)                        \
              acc[mi][ni][q] += bv;                                            \
      }                                                                        \
    }                                                                          \
    /* boundary: drain tile t+1 (issued 2 tiles ago) */                        \
    if (t_ < NT - 3) { asm volatile("s_waitcnt vmcnt(8)" ::: "memory"); }      \
    else if (t_ == NT - 3) { asm volatile("s_waitcnt vmcnt(4)" ::: "memory"); }\
    else if (t_ == NT - 2) { asm volatile("s_waitcnt vmcnt(0)" ::: "memory"); }\
    if (t_ < NT - 1) { __builtin_amdgcn_s_barrier(); SB; }                     \
  }

  for (int tt = 0; tt < NT; tt += 4) {
    TILE_BODY(tt, 0);
    TILE_BODY(tt + 1, 1);
    TILE_BODY(tt + 2, 2);
    TILE_BODY(tt + 3, 3);
  }

  // epilogue: atomicAdd acc*g[eL] + sum_{e in half} g[e]*be[e,col] into out
  const int eL = kh * 8 + 7;
  float bv[8][4];
#pragma unroll
  for (int e8 = 0; e8 < 8; ++e8)
#pragma unroll
    for (int ni = 0; ni < 4; ++ni)
      bv[e8][ni] = be[(kh * 8 + e8) * DOUT + bcol + wn * 64 + ni * 16 + l15];
#pragma unroll
  for (int mi = 0; mi < 8; ++mi) {
    const int rb = wm * 128 + mi * 16 + l4 * 4;
#pragma unroll
    for (int q = 0; q < 4; ++q) {
      const int row = rb + q;
      const float gf = gs[row][eL];
      float b0 = 0.f, b1 = 0.f, b2 = 0.f, b3 = 0.f;
#pragma unroll
      for (int e8 = 0; e8 < 8; ++e8) {
        const float ge = gs[row][kh * 8 + e8];
        b0 = fmaf(ge, bv[e8][0], b0);
        b1 = fmaf(ge, bv[e8][1], b1);
        b2 = fmaf(ge, bv[e8][2], b2);
        b3 = fmaf(ge, bv[e8][3], b3);
      }
      float* const orp =
          out + (size_t)(brow + row) * DOUT + bcol + wn * 64 + l15;
      atomicAdd(orp,      fmaf(acc[mi][0][q], gf, b0));
      atomicAdd(orp + 16, fmaf(acc[mi][1][q], gf, b1));
      atomicAdd(orp + 32, fmaf(acc[mi][2][q], gf, b2));
      atomicAdd(orp + 48, fmaf(acc[mi][3][q], gf, b3));
    }
  }
#undef TILE_BODY
#undef MFMA_P
#undef RD_A
#undef RD_B
#undef STA
#undef STB
}

// ---------------------------------------------------------------------------
extern "C" void kernel_launch(void* const* d_in, const int* in_sizes, int n_in,
                              void* d_out, int out_size, void* d_ws, size_t ws_size,
                              hipStream_t stream) {
  const float* x  = (const float*)d_in[0];
  const float* Wg = (const float*)d_in[1];
  const float* bg = (const float*)d_in[2];
  const float* We = (const float*)d_in[3];
  const float* be = (const float*)d_in[4];
  float* out = (float*)d_out;

  // ws: xbf 16MB | WeT 32MB | g 512KB
  char* ws = (char*)d_ws;
  unsigned short* xbf = (unsigned short*)ws;
  unsigned short* WeT = (unsigned short*)(ws + (size_t)NB * DIN * 2);
  float* g = (float*)(ws + (size_t)NB * DIN * 2 + (size_t)NE * DIN * DOUT * 2);

  hipMemsetAsync(out, 0, (size_t)NB * DOUT * sizeof(float), stream);
  gate_cast_kernel<<<dim3(NB / 4), 256, 0, stream>>>(x, Wg, bg, g, xbf);
  we_transpose_kernel<<<dim3(DOUT / 64, DIN / 64, NE), 256, 0, stream>>>(We, WeT);
  moe_gemm_kernel<<<dim3(256), 512, 0, stream>>>(xbf, WeT, g, be, out);
}